// Round 4
// baseline (485.320 us; speedup 1.0000x reference)
//
#include <hip/hip_runtime.h>
#include <stdint.h>

// BiMultiHeadAttention (GLIP bi-attention), MI355X bf16 MFMA pipeline.
// B=32 VN=576 LN=128 E=1024 H=16 D=64, V_DIM=1024 L_DIM=768, SCALE=0.25.

typedef unsigned short bfu;   // bf16 storage
typedef __attribute__((ext_vector_type(4))) float f32x4;
typedef __attribute__((ext_vector_type(8))) short short8;
typedef __attribute__((ext_vector_type(4))) unsigned short u16x4;

#define MFMA16(a,b,c) __builtin_amdgcn_mfma_f32_16x16x32_bf16((a),(b),(c),0,0,0)
#define SCALE_QK 0.25f

__device__ __forceinline__ unsigned short f2bf(float x) {
  unsigned int u = __float_as_uint(x);
  u += 0x7fffu + ((u >> 16) & 1u);   // round-to-nearest-even
  return (unsigned short)(u >> 16);
}

__device__ __forceinline__ void gload_lds16(const void* g, void* l) {
  __builtin_amdgcn_global_load_lds(
      reinterpret_cast<__attribute__((address_space(1))) void*>(
          reinterpret_cast<uintptr_t>(g)),
      reinterpret_cast<__attribute__((address_space(3))) void*>(
          (uint32_t)reinterpret_cast<uintptr_t>(l)),
      16, 0, 0);
}

// ---------------------------------------------------------------- converts
__global__ void cvt_f32_bf16(const float* __restrict__ x, bfu* __restrict__ y, int n4) {
  for (int i = blockIdx.x * blockDim.x + threadIdx.x; i < n4; i += gridDim.x * blockDim.x) {
    const float4 f = *reinterpret_cast<const float4*>(x + (size_t)i * 4);
    u16x4 o;
    o[0] = f2bf(f.x); o[1] = f2bf(f.y); o[2] = f2bf(f.z); o[3] = f2bf(f.w);
    *reinterpret_cast<u16x4*>(y + (size_t)i * 4) = o;
  }
}

struct CvtArgs {
  const float* src[7];
  bfu* dst[7];
  int n4[7];
};

__global__ void cvt_multi(CvtArgs a) {
  const int s = blockIdx.y;
  const float* __restrict__ x = a.src[s];
  bfu* __restrict__ y = a.dst[s];
  const int n4 = a.n4[s];
  for (int i = blockIdx.x * blockDim.x + threadIdx.x; i < n4; i += gridDim.x * blockDim.x) {
    const float4 f = *reinterpret_cast<const float4*>(x + (size_t)i * 4);
    u16x4 o;
    o[0] = f2bf(f.x); o[1] = f2bf(f.y); o[2] = f2bf(f.z); o[3] = f2bf(f.w);
    *reinterpret_cast<u16x4*>(y + (size_t)i * 4) = o;
  }
}

// ---------------------------------------------------------------- GEMM (C = A @ W^T + bias), m97 structure
// A: M x K bf16 row-major; W: N x K bf16 row-major. M%128==0, N%128==0, K%32==0.
// Epilogue: col <  colsplit -> row-major with leading dim ldc (Cf f32 if non-null, else Cb bf16).
//           col >= colsplit -> Ct transposed bf16: col'=col-colsplit, row=(bb,q0) via R:
//                              Ct[((bb*16 + col'>>6)*64 + (col'&63))*R + q0].
__global__ __launch_bounds__(256) void gemm_bt(
    const bfu* __restrict__ A, const bfu* __restrict__ W, const float* __restrict__ bias,
    bfu* __restrict__ Cb, float* __restrict__ Cf, bfu* __restrict__ Ct, int R, int colsplit,
    int ldc, int M, int N, int K, int nbn)
{
  __shared__ bfu As[128 * 32];
  __shared__ bfu Bs[128 * 32];
  const int nbm = M >> 7;
  const int bid = blockIdx.x;
  int bm, bn;
  if ((nbm & 7) == 0) {             // bijective XCD-aware swizzle
    const int xcd = bid & 7, j = bid >> 3;
    const int jm = j / nbn;
    bm = xcd * (nbm >> 3) + jm;
    bn = j - jm * nbn;
  } else { bm = bid / nbn; bn = bid - (bid / nbn) * nbn; }

  const int t = threadIdx.x, l = t & 63, w = t >> 6;
  const int g = l >> 4, c = l & 15;
  const int wr = (w >> 1) * 64, wc = (w & 1) * 64;

  f32x4 zero = {0.f, 0.f, 0.f, 0.f};
  f32x4 acc[4][4];
  for (int m = 0; m < 4; ++m)
    for (int n = 0; n < 4; ++n) acc[m][n] = zero;

  const int rowA = l >> 2;          // 0..15 within 16-row chunk
  const int kb   = (l & 3) * 16;    // byte offset within 64B row

  for (int k0 = 0; k0 < K; k0 += 32) {
#pragma unroll
    for (int i = 0; i < 2; ++i) {
      int chunk = w * 2 + i;
      int r = chunk * 16 + rowA;
      const char* ga = (const char*)(A + (size_t)(bm * 128 + r) * K + k0) + kb;
      const char* gb = (const char*)(W + (size_t)(bn * 128 + r) * K + k0) + kb;
      gload_lds16(ga, (char*)As + chunk * 1024);
      gload_lds16(gb, (char*)Bs + chunk * 1024);
    }
    __syncthreads();
    short8 a[4], bf[4];
#pragma unroll
    for (int m = 0; m < 4; ++m)
      a[m] = *reinterpret_cast<const short8*>(&As[(wr + m * 16 + c) * 32 + g * 8]);
#pragma unroll
    for (int n = 0; n < 4; ++n)
      bf[n] = *reinterpret_cast<const short8*>(&Bs[(wc + n * 16 + c) * 32 + g * 8]);
#pragma unroll
    for (int m = 0; m < 4; ++m)
#pragma unroll
      for (int n = 0; n < 4; ++n)
        acc[m][n] = MFMA16(a[m], bf[n], acc[m][n]);
    __syncthreads();
  }

#pragma unroll
  for (int n = 0; n < 4; ++n) {
    const int col = bn * 128 + wc + n * 16 + c;
    const float bs = bias[col];
    if (col >= colsplit) {
      const int colp = col - colsplit;
      const int hh = colp >> 6, dd = colp & 63;
#pragma unroll
      for (int m = 0; m < 4; ++m) {
        const int row0 = bm * 128 + wr + m * 16 + g * 4;
        const int bb = row0 / R, q0 = row0 - bb * R;
        u16x4 pk;
#pragma unroll
        for (int r = 0; r < 4; ++r) pk[r] = f2bf(acc[m][n][r] + bs);
        *reinterpret_cast<u16x4*>(Ct + ((size_t)(bb * 16 + hh) * 64 + dd) * R + q0) = pk;
      }
    } else {
#pragma unroll
      for (int m = 0; m < 4; ++m) {
        const int row0 = bm * 128 + wr + m * 16 + g * 4;
#pragma unroll
        for (int r = 0; r < 4; ++r) {
          float val = acc[m][n][r] + bs;
          size_t idx = (size_t)(row0 + r) * ldc + col;
          if (Cf) Cf[idx] = val;
          else    Cb[idx] = f2bf(val);
        }
      }
    }
  }
}

// ---------------------------------------------------------------- fused bidirectional attention, one block per (b,h)
// Whole P^T (128 k x 576 q, bf16) lives in LDS, swizzled: elem(k,q) at k*576 + (q ^ ((k&7)<<3)).
// Phase 1 (16 waves x 36 qtiles): S=QK^T, P=exp(S*scale+mask[k]) -> LDS + rowsum-normalized
// xv = P @ LV; colsum partials accumulated (mask factor cancels in the xl softmax).
// Phase 2: wave -> (ktile, d-half): xl = P^T @ VV / colsum.
__global__ __launch_bounds__(1024, 4) void attn_bh(
    const bfu* __restrict__ Q, const bfu* __restrict__ Kl,
    const bfu* __restrict__ LVt, const bfu* __restrict__ VVt,
    const float* __restrict__ mask,
    bfu* __restrict__ xv, bfu* __restrict__ xl)
{
  __shared__ short P[128 * 576];      // 147456 B
  __shared__ float colpart[16][128];  // 8192 B
  __shared__ float colinv[128];       // 512 B

  const int bh = blockIdx.x;
  const int b = bh >> 4, h = bh & 15;
  const int t = threadIdx.x, l = t & 63, w = t >> 6;
  const int g = l >> 4, c = l & 15;

  const bfu* Qp  = Q   + ((size_t)b * 576 * 1024 + h * 64);
  const bfu* Kp  = Kl  + ((size_t)b * 128 * 1024 + h * 64);
  const bfu* LVp = LVt + (size_t)bh * 64 * 128;
  const bfu* VVp = VVt + (size_t)bh * 64 * 576;
  const f32x4 zero = {0.f, 0.f, 0.f, 0.f};

  float mk[8];
#pragma unroll
  for (int kt = 0; kt < 8; ++kt) mk[kt] = mask[kt * 16 + c];

  // ---- phase 1: qtiles 0..35 over 16 waves (waves 0-3: 3 tiles, 4-15: 2 tiles)
  const int qt0 = (w < 4) ? w * 3 : 12 + (w - 4) * 2;
  const int nqt = (w < 4) ? 3 : 2;
  float colacc[8] = {0, 0, 0, 0, 0, 0, 0, 0};

  for (int iq = 0; iq < nqt; ++iq) {
    const int qt = qt0 + iq;
    f32x4 sacc[8];
#pragma unroll
    for (int kt = 0; kt < 8; ++kt) sacc[kt] = zero;
#pragma unroll
    for (int kk = 0; kk < 2; ++kk) {
      short8 aq = *reinterpret_cast<const short8*>(Qp + (size_t)(qt * 16 + c) * 1024 + kk * 32 + g * 8);
#pragma unroll
      for (int kt = 0; kt < 8; ++kt) {
        short8 bk = *reinterpret_cast<const short8*>(Kp + (size_t)(kt * 16 + c) * 1024 + kk * 32 + g * 8);
        sacc[kt] = MFMA16(aq, bk, sacc[kt]);
      }
    }
    // P = exp(S*scale + mask[k]); write swizzled P^T to LDS; accumulate sums.
    float rs[4] = {0, 0, 0, 0};
#pragma unroll
    for (int kt = 0; kt < 8; ++kt) {
      const int krow = kt * 16 + c;
      short* Prow = P + krow * 576;
      const int sw = (c & 7) << 3;
#pragma unroll
      for (int r = 0; r < 4; ++r) {
        float Ev = __expf(fmaf(sacc[kt][r], SCALE_QK, mk[kt]));
        rs[r] += Ev;
        colacc[kt] += Ev;
        Prow[(qt * 16 + g * 4 + r) ^ sw] = (short)f2bf(Ev);
      }
    }
#pragma unroll
    for (int r = 0; r < 4; ++r) {
      rs[r] += __shfl_xor(rs[r], 1);
      rs[r] += __shfl_xor(rs[r], 2);
      rs[r] += __shfl_xor(rs[r], 4);
      rs[r] += __shfl_xor(rs[r], 8);
    }
    // xv tile = P(16x128) @ LV(128x64); A-frags gathered from LDS P^T.
    short8 av[4];
#pragma unroll
    for (int kc = 0; kc < 4; ++kc) {
#pragma unroll
      for (int j = 0; j < 8; ++j)
        av[kc][j] = P[(kc * 32 + g * 8 + j) * 576 + ((qt * 16 + c) ^ (j << 3))];
    }
    f32x4 oxv[4];
#pragma unroll
    for (int dt = 0; dt < 4; ++dt) oxv[dt] = zero;
#pragma unroll
    for (int dt = 0; dt < 4; ++dt)
#pragma unroll
      for (int kc = 0; kc < 4; ++kc) {
        short8 bv = *reinterpret_cast<const short8*>(LVp + (size_t)(dt * 16 + c) * 128 + kc * 32 + g * 8);
        oxv[dt] = MFMA16(av[kc], bv, oxv[dt]);
      }
#pragma unroll
    for (int r = 0; r < 4; ++r) rs[r] = 1.0f / rs[r];
#pragma unroll
    for (int dt = 0; dt < 4; ++dt)
#pragma unroll
      for (int r = 0; r < 4; ++r) {
        float val = oxv[dt][r] * rs[r];
        xv[(size_t)(b * 576 + qt * 16 + g * 4 + r) * 1024 + h * 64 + dt * 16 + c] = f2bf(val);
      }
  }

  // ---- column-sum reduce (deterministic): per-wave -> LDS -> 128 lanes
#pragma unroll
  for (int kt = 0; kt < 8; ++kt) {
    colacc[kt] += __shfl_xor(colacc[kt], 16);
    colacc[kt] += __shfl_xor(colacc[kt], 32);
  }
  if (g == 0) {
#pragma unroll
    for (int kt = 0; kt < 8; ++kt) colpart[w][kt * 16 + c] = colacc[kt];
  }
  __syncthreads();
  if (t < 128) {
    float s = 0.f;
#pragma unroll
    for (int ww = 0; ww < 16; ++ww) s += colpart[ww][t];
    colinv[t] = 1.0f / s;
  }
  __syncthreads();

  // ---- phase 2: wave -> kt = w>>1 (8), d-half = (w&1)*2 (2 dt tiles)
  const int kt = w >> 1;
  const int dt0 = (w & 1) * 2;
  const int krow = kt * 16 + c;
  const short* Prow = P + krow * 576;
  const int sw = (c & 7) << 3;

  float ci[4];
#pragma unroll
  for (int r = 0; r < 4; ++r) ci[r] = colinv[kt * 16 + g * 4 + r];

  f32x4 oxl[2];
  oxl[0] = zero; oxl[1] = zero;
  for (int p = 0; p < 18; ++p) {
    short8 ap = *reinterpret_cast<const short8*>(Prow + ((p * 32 + g * 8) ^ sw));
#pragma unroll
    for (int dti = 0; dti < 2; ++dti) {
      short8 bv = *reinterpret_cast<const short8*>(VVp + (size_t)((dt0 + dti) * 16 + c) * 576 + p * 32 + g * 8);
      oxl[dti] = MFMA16(ap, bv, oxl[dti]);
    }
  }
#pragma unroll
  for (int dti = 0; dti < 2; ++dti)
#pragma unroll
    for (int r = 0; r < 4; ++r) {
      float val = oxl[dti][r] * ci[r];
      xl[(size_t)(b * 128 + kt * 16 + g * 4 + r) * 1024 + h * 64 + (dt0 + dti) * 16 + c] = f2bf(val);
    }
}

// ---------------------------------------------------------------- host
static inline int cvt_grid(int n4) {
  int g = (n4 + 255) / 256;
  return g > 4096 ? 4096 : g;
}

extern "C" void kernel_launch(void* const* d_in, const int* in_sizes, int n_in,
                              void* d_out, int out_size, void* d_ws, size_t ws_size,
                              hipStream_t stream)
{
  const float* v    = (const float*)d_in[0];
  const float* lx   = (const float*)d_in[1];
  const float* mask = (const float*)d_in[2];
  const float* Wvq  = (const float*)d_in[3];
  const float* bvq  = (const float*)d_in[4];
  const float* Wlk  = (const float*)d_in[5];
  const float* blk  = (const float*)d_in[6];
  const float* Wvv  = (const float*)d_in[7];
  const float* bvv  = (const float*)d_in[8];
  const float* Wlv  = (const float*)d_in[9];
  const float* blv  = (const float*)d_in[10];
  const float* Wvo  = (const float*)d_in[11];
  const float* bvo  = (const float*)d_in[12];
  const float* Wlo  = (const float*)d_in[13];
  const float* blo  = (const float*)d_in[14];

  float* out_xv = (float*)d_out;                       // 18432 x 1024
  float* out_xl = out_xv + (size_t)18432 * 1024;       // 4096 x 768

  bfu* ws   = (bfu*)d_ws;
  bfu* vb   = ws;                      // 18874368 (later aliased as xv bf16)
  bfu* lb   = vb   + 18874368;         // 3145728
  bfu* wqv  = lb   + 3145728;          // 2097152  [Wvq ; Wvv]  (2048 x 1024)
  bfu* wklv = wqv  + 2097152;          // 1572864  [Wlk ; Wlv]  (2048 x 768)
  bfu* wvo  = wklv + 1572864;          // 1048576
  bfu* wlo  = wvo  + 1048576;          // 786432
  bfu* Qb   = wlo  + 786432;           // 18874368  [18432][1024] bf16
  bfu* VVt  = Qb   + 18874368;         // 18874368  [bh][64][576]
  bfu* Kb   = VVt  + 18874368;         // 4194304   [4096][1024] (later aliased as xl bf16)
  bfu* LVt  = Kb   + 4194304;          // 4194304   [bh][64][128]
  float* biasqv = (float*)(LVt + 4194304);   // 2048 f32  [bvq ; bvv]
  float* biaskl = biasqv + 2048;             // 2048 f32  [blk ; blv]

  // 1) converts + bias concat (d2d async copies are graph-capture safe)
  cvt_f32_bf16<<<cvt_grid(18874368 / 4), 256, 0, stream>>>(v, vb, 18874368 / 4);
  CvtArgs ca;
  ca.src[0] = lx;  ca.dst[0] = lb;             ca.n4[0] = 3145728 / 4;
  ca.src[1] = Wvq; ca.dst[1] = wqv;            ca.n4[1] = 1048576 / 4;
  ca.src[2] = Wvv; ca.dst[2] = wqv + 1048576;  ca.n4[2] = 1048576 / 4;
  ca.src[3] = Wlk; ca.dst[3] = wklv;           ca.n4[3] = 786432 / 4;
  ca.src[4] = Wlv; ca.dst[4] = wklv + 786432;  ca.n4[4] = 786432 / 4;
  ca.src[5] = Wvo; ca.dst[5] = wvo;            ca.n4[5] = 1048576 / 4;
  ca.src[6] = Wlo; ca.dst[6] = wlo;            ca.n4[6] = 786432 / 4;
  cvt_multi<<<dim3(1024, 7), 256, 0, stream>>>(ca);
  hipMemcpyAsync(biasqv,        bvq, 1024 * sizeof(float), hipMemcpyDeviceToDevice, stream);
  hipMemcpyAsync(biasqv + 1024, bvv, 1024 * sizeof(float), hipMemcpyDeviceToDevice, stream);
  hipMemcpyAsync(biaskl,        blk, 1024 * sizeof(float), hipMemcpyDeviceToDevice, stream);
  hipMemcpyAsync(biaskl + 1024, blv, 1024 * sizeof(float), hipMemcpyDeviceToDevice, stream);

  // 2) fused projection GEMMs: [Q | VVt] and [K | LVt]; row-major halves have ldc=1024
  gemm_bt<<<144 * 16, 256, 0, stream>>>(vb, wqv,  biasqv, Qb, nullptr, VVt, 576, 1024, 1024,
                                        18432, 2048, 1024, 16);
  gemm_bt<<<32 * 16,  256, 0, stream>>>(lb, wklv, biaskl, Kb, nullptr, LVt, 128, 1024, 1024,
                                        4096, 2048, 768, 16);

  // 3) fused bidirectional attention (xv -> vb alias, xl -> Kb alias)
  attn_bh<<<512, 1024, 0, stream>>>(Qb, Kb, LVt, VVt, mask, vb, Kb);

  // 4) output GEMMs (f32 out)
  gemm_bt<<<144 * 8, 256, 0, stream>>>(vb, wvo, bvo, nullptr, out_xv, nullptr, 0, 1024, 1024,
                                       18432, 1024, 1024, 8);
  gemm_bt<<<32 * 6,  256, 0, stream>>>(Kb, wlo, blo, nullptr, out_xl, nullptr, 0, 768, 768,
                                       4096, 768, 1024, 6);
}

// Round 5
// 405.861 us; speedup vs baseline: 1.1958x; 1.1958x over previous
//
#include <hip/hip_runtime.h>
#include <stdint.h>

// BiMultiHeadAttention (GLIP bi-attention), MI355X bf16 MFMA pipeline.
// B=32 VN=576 LN=128 E=1024 H=16 D=64, V_DIM=1024 L_DIM=768, SCALE=0.25.

typedef unsigned short bfu;   // bf16 storage
typedef __attribute__((ext_vector_type(4))) float f32x4;
typedef __attribute__((ext_vector_type(8))) short short8;
typedef __attribute__((ext_vector_type(4))) unsigned short u16x4;

#define MFMA16(a,b,c) __builtin_amdgcn_mfma_f32_16x16x32_bf16((a),(b),(c),0,0,0)
#define SCALE_QK 0.25f

__device__ __forceinline__ unsigned short f2bf(float x) {
  unsigned int u = __float_as_uint(x);
  u += 0x7fffu + ((u >> 16) & 1u);   // round-to-nearest-even
  return (unsigned short)(u >> 16);
}

__device__ __forceinline__ void gload_lds16(const void* g, void* l) {
  __builtin_amdgcn_global_load_lds(
      reinterpret_cast<__attribute__((address_space(1))) void*>(
          reinterpret_cast<uintptr_t>(g)),
      reinterpret_cast<__attribute__((address_space(3))) void*>(
          (uint32_t)reinterpret_cast<uintptr_t>(l)),
      16, 0, 0);
}

// ---------------------------------------------------------------- converts
__global__ void cvt_f32_bf16(const float* __restrict__ x, bfu* __restrict__ y, int n4) {
  for (int i = blockIdx.x * blockDim.x + threadIdx.x; i < n4; i += gridDim.x * blockDim.x) {
    const float4 f = *reinterpret_cast<const float4*>(x + (size_t)i * 4);
    u16x4 o;
    o[0] = f2bf(f.x); o[1] = f2bf(f.y); o[2] = f2bf(f.z); o[3] = f2bf(f.w);
    *reinterpret_cast<u16x4*>(y + (size_t)i * 4) = o;
  }
}

struct CvtArgs {
  const float* src[7];
  bfu* dst[7];
  int n4[7];
};

__global__ void cvt_multi(CvtArgs a) {
  const int s = blockIdx.y;
  const float* __restrict__ x = a.src[s];
  bfu* __restrict__ y = a.dst[s];
  const int n4 = a.n4[s];
  for (int i = blockIdx.x * blockDim.x + threadIdx.x; i < n4; i += gridDim.x * blockDim.x) {
    const float4 f = *reinterpret_cast<const float4*>(x + (size_t)i * 4);
    u16x4 o;
    o[0] = f2bf(f.x); o[1] = f2bf(f.y); o[2] = f2bf(f.z); o[3] = f2bf(f.w);
    *reinterpret_cast<u16x4*>(y + (size_t)i * 4) = o;
  }
}

// ---------------------------------------------------------------- GEMM (C = A @ W^T + bias), m97 structure
// A: M x K bf16 row-major; W: N x K bf16 row-major. M%128==0, N%128==0, K%32==0.
// Epilogue: col <  colsplit -> row-major with leading dim ldc (Cf f32 if non-null, else Cb bf16).
//           col >= colsplit -> Ct transposed bf16: col'=col-colsplit, row=(bb,q0) via R:
//                              Ct[((bb*16 + col'>>6)*64 + (col'&63))*R + q0].
__global__ __launch_bounds__(256) void gemm_bt(
    const bfu* __restrict__ A, const bfu* __restrict__ W, const float* __restrict__ bias,
    bfu* __restrict__ Cb, float* __restrict__ Cf, bfu* __restrict__ Ct, int R, int colsplit,
    int ldc, int M, int N, int K, int nbn)
{
  __shared__ bfu As[128 * 32];
  __shared__ bfu Bs[128 * 32];
  const int nbm = M >> 7;
  const int bid = blockIdx.x;
  int bm, bn;
  if ((nbm & 7) == 0) {             // bijective XCD-aware swizzle
    const int xcd = bid & 7, j = bid >> 3;
    const int jm = j / nbn;
    bm = xcd * (nbm >> 3) + jm;
    bn = j - jm * nbn;
  } else { bm = bid / nbn; bn = bid - (bid / nbn) * nbn; }

  const int t = threadIdx.x, l = t & 63, w = t >> 6;
  const int g = l >> 4, c = l & 15;
  const int wr = (w >> 1) * 64, wc = (w & 1) * 64;

  f32x4 zero = {0.f, 0.f, 0.f, 0.f};
  f32x4 acc[4][4];
  for (int m = 0; m < 4; ++m)
    for (int n = 0; n < 4; ++n) acc[m][n] = zero;

  const int rowA = l >> 2;          // 0..15 within 16-row chunk
  const int kb   = (l & 3) * 16;    // byte offset within 64B row

  for (int k0 = 0; k0 < K; k0 += 32) {
#pragma unroll
    for (int i = 0; i < 2; ++i) {
      int chunk = w * 2 + i;
      int r = chunk * 16 + rowA;
      const char* ga = (const char*)(A + (size_t)(bm * 128 + r) * K + k0) + kb;
      const char* gb = (const char*)(W + (size_t)(bn * 128 + r) * K + k0) + kb;
      gload_lds16(ga, (char*)As + chunk * 1024);
      gload_lds16(gb, (char*)Bs + chunk * 1024);
    }
    __syncthreads();
    short8 a[4], bf[4];
#pragma unroll
    for (int m = 0; m < 4; ++m)
      a[m] = *reinterpret_cast<const short8*>(&As[(wr + m * 16 + c) * 32 + g * 8]);
#pragma unroll
    for (int n = 0; n < 4; ++n)
      bf[n] = *reinterpret_cast<const short8*>(&Bs[(wc + n * 16 + c) * 32 + g * 8]);
#pragma unroll
    for (int m = 0; m < 4; ++m)
#pragma unroll
      for (int n = 0; n < 4; ++n)
        acc[m][n] = MFMA16(a[m], bf[n], acc[m][n]);
    __syncthreads();
  }

#pragma unroll
  for (int n = 0; n < 4; ++n) {
    const int col = bn * 128 + wc + n * 16 + c;
    const float bs = bias[col];
    if (col >= colsplit) {
      const int colp = col - colsplit;
      const int hh = colp >> 6, dd = colp & 63;
#pragma unroll
      for (int m = 0; m < 4; ++m) {
        const int row0 = bm * 128 + wr + m * 16 + g * 4;
        const int bb = row0 / R, q0 = row0 - bb * R;
        u16x4 pk;
#pragma unroll
        for (int r = 0; r < 4; ++r) pk[r] = f2bf(acc[m][n][r] + bs);
        *reinterpret_cast<u16x4*>(Ct + ((size_t)(bb * 16 + hh) * 64 + dd) * R + q0) = pk;
      }
    } else {
#pragma unroll
      for (int m = 0; m < 4; ++m) {
        const int row0 = bm * 128 + wr + m * 16 + g * 4;
#pragma unroll
        for (int r = 0; r < 4; ++r) {
          float val = acc[m][n][r] + bs;
          size_t idx = (size_t)(row0 + r) * ldc + col;
          if (Cf) Cf[idx] = val;
          else    Cb[idx] = f2bf(val);
        }
      }
    }
  }
}

// ---------------------------------------------------------------- swizzled per-wave P-tile offsets
__device__ __forceinline__ int pvt_off(int q, int kbyte) { return q * 256 + (kbyte ^ ((q & 7) << 4)); }

// ---------------------------------------------------------------- attention stage A: xv + P^T + colsum partials
// ONE WAVE per block: grid qt*512 + bh (18432 blocks, 64 threads).
// No block barrier; per-wave private LDS P tile; colpart at qt granularity (36 per bh).
__global__ __launch_bounds__(64) void attn_xv(
    const bfu* __restrict__ Q, const bfu* __restrict__ Kl,
    const bfu* __restrict__ LVt, const float* __restrict__ mask,
    bfu* __restrict__ xv, bfu* __restrict__ PT, float* __restrict__ colpart)
{
  __shared__ short PvT[2048];         // 16x128 bf16 P tile, swizzled (4 KB)

  const int blk = blockIdx.x;
  const int bh = blk & 511, qt = blk >> 9;   // same-bh blocks stride 512 -> same XCD
  const int b = bh >> 4, h = bh & 15;
  const int l = threadIdx.x;
  const int g = l >> 4, c = l & 15;

  const bfu* Qp   = Q   + ((size_t)b * 576 * 1024 + h * 64);
  const bfu* Kp   = Kl  + ((size_t)b * 128 * 1024 + h * 64);
  const bfu* LVp  = LVt + (size_t)bh * 64 * 128;
  const f32x4 zero = {0.f, 0.f, 0.f, 0.f};

  float mk[8];
#pragma unroll
  for (int kt = 0; kt < 8; ++kt) mk[kt] = mask[kt * 16 + c];

  // S = Q K^T for this 16q x 128k tile
  f32x4 sacc[8];
#pragma unroll
  for (int kt = 0; kt < 8; ++kt) sacc[kt] = zero;
#pragma unroll
  for (int kk = 0; kk < 2; ++kk) {
    short8 aq = *reinterpret_cast<const short8*>(Qp + (size_t)(qt * 16 + c) * 1024 + kk * 32 + g * 8);
#pragma unroll
    for (int kt = 0; kt < 8; ++kt) {
      short8 bk = *reinterpret_cast<const short8*>(Kp + (size_t)(kt * 16 + c) * 1024 + kk * 32 + g * 8);
      sacc[kt] = MFMA16(aq, bk, sacc[kt]);
    }
  }

  // P = exp(S*scale + mask[k]); softmax-over-q is invariant to the per-k mask shift,
  // so this single P serves both softmaxes.
  char* myPv = (char*)&PvT[0];
  float rs[4] = {0, 0, 0, 0};
  float colacc[8];
#pragma unroll
  for (int kt = 0; kt < 8; ++kt) {
    u16x4 pk;
    float ca = 0.f;
#pragma unroll
    for (int r = 0; r < 4; ++r) {
      float Ev = __expf(fmaf(sacc[kt][r], SCALE_QK, mk[kt]));
      rs[r] += Ev;
      ca += Ev;
      pk[r] = f2bf(Ev);
      *reinterpret_cast<unsigned short*>(myPv + pvt_off(g * 4 + r, 2 * (kt * 16 + c))) = pk[r];
    }
    colacc[kt] = ca;
    // P^T store: rows k, cols q (contiguous 4 q per lane)
    *reinterpret_cast<u16x4*>(PT + ((size_t)bh * 128 + kt * 16 + c) * 576 + qt * 16 + g * 4) = pk;
  }
  // row-sum reduce across the 16 k-lanes (c)
#pragma unroll
  for (int r = 0; r < 4; ++r) {
    rs[r] += __shfl_xor(rs[r], 1);
    rs[r] += __shfl_xor(rs[r], 2);
    rs[r] += __shfl_xor(rs[r], 4);
    rs[r] += __shfl_xor(rs[r], 8);
  }

  // xv tile = P(16x128) @ LV(128x64)
  short8 av[4];
#pragma unroll
  for (int kc = 0; kc < 4; ++kc)
    av[kc] = *reinterpret_cast<const short8*>(myPv + pvt_off(c, kc * 64 + g * 16));
  f32x4 oxv[4];
#pragma unroll
  for (int dt = 0; dt < 4; ++dt) oxv[dt] = zero;
#pragma unroll
  for (int dt = 0; dt < 4; ++dt)
#pragma unroll
    for (int kc = 0; kc < 4; ++kc) {
      short8 bv = *reinterpret_cast<const short8*>(LVp + (size_t)(dt * 16 + c) * 128 + kc * 32 + g * 8);
      oxv[dt] = MFMA16(av[kc], bv, oxv[dt]);
    }
#pragma unroll
  for (int r = 0; r < 4; ++r) rs[r] = 1.0f / rs[r];
#pragma unroll
  for (int dt = 0; dt < 4; ++dt)
#pragma unroll
    for (int r = 0; r < 4; ++r) {
      float val = oxv[dt][r] * rs[r];
      xv[(size_t)(b * 576 + qt * 16 + g * 4 + r) * 1024 + h * 64 + dt * 16 + c] = f2bf(val);
    }

  // column-sum partial for this 16-q tile (deterministic, no atomics, no barrier)
#pragma unroll
  for (int kt = 0; kt < 8; ++kt) {
    colacc[kt] += __shfl_xor(colacc[kt], 16);
    colacc[kt] += __shfl_xor(colacc[kt], 32);
  }
  if (g == 0) {
#pragma unroll
    for (int kt = 0; kt < 8; ++kt)
      colpart[(size_t)(bh * 36 + qt) * 128 + kt * 16 + c] = colacc[kt];
  }
}

// ---------------------------------------------------------------- attention stage B: xl = P^T @ VV / colsum
// ONE WAVE per block: grid kt*512 + bh (4096 blocks, 64 threads).
__global__ __launch_bounds__(64) void attn_xl(
    const bfu* __restrict__ PT, const bfu* __restrict__ VVt,
    const float* __restrict__ colpart, bfu* __restrict__ xl)
{
  const int blk = blockIdx.x;
  const int bh = blk & 511, kt = blk >> 9;   // ktile 0..7
  const int b = bh >> 4, h = bh & 15;
  const int l = threadIdx.x;
  const int g = l >> 4, c = l & 15;

  const bfu* PTb  = PT  + ((size_t)bh * 128 + kt * 16 + c) * 576;
  const bfu* VVp  = VVt + (size_t)bh * 64 * 576;
  const f32x4 zero = {0.f, 0.f, 0.f, 0.f};

  // colsum for k = kt*16 + c (replicated across g), then redistribute per-r via shfl
  float s = 0.f;
  const float* cp = colpart + (size_t)bh * 36 * 128 + kt * 16 + c;
#pragma unroll
  for (int qc = 0; qc < 36; ++qc) s += cp[qc * 128];
  float sinv = 1.0f / s;
  float ci[4];
#pragma unroll
  for (int r = 0; r < 4; ++r) ci[r] = __shfl(sinv, g * 4 + r);

  f32x4 acc[4];
#pragma unroll
  for (int dt = 0; dt < 4; ++dt) acc[dt] = zero;

  for (int p = 0; p < 18; ++p) {
    short8 ap = *reinterpret_cast<const short8*>(PTb + p * 32 + g * 8);
#pragma unroll
    for (int dt = 0; dt < 4; ++dt) {
      short8 bv = *reinterpret_cast<const short8*>(VVp + (size_t)(dt * 16 + c) * 576 + p * 32 + g * 8);
      acc[dt] = MFMA16(ap, bv, acc[dt]);
    }
  }

#pragma unroll
  for (int dt = 0; dt < 4; ++dt)
#pragma unroll
    for (int r = 0; r < 4; ++r) {
      float val = acc[dt][r] * ci[r];
      xl[(size_t)(b * 128 + kt * 16 + g * 4 + r) * 1024 + h * 64 + dt * 16 + c] = f2bf(val);
    }
}

// ---------------------------------------------------------------- host
static inline int cvt_grid(int n4) {
  int g = (n4 + 255) / 256;
  return g > 4096 ? 4096 : g;
}

extern "C" void kernel_launch(void* const* d_in, const int* in_sizes, int n_in,
                              void* d_out, int out_size, void* d_ws, size_t ws_size,
                              hipStream_t stream)
{
  const float* v    = (const float*)d_in[0];
  const float* lx   = (const float*)d_in[1];
  const float* mask = (const float*)d_in[2];
  const float* Wvq  = (const float*)d_in[3];
  const float* bvq  = (const float*)d_in[4];
  const float* Wlk  = (const float*)d_in[5];
  const float* blk  = (const float*)d_in[6];
  const float* Wvv  = (const float*)d_in[7];
  const float* bvv  = (const float*)d_in[8];
  const float* Wlv  = (const float*)d_in[9];
  const float* blv  = (const float*)d_in[10];
  const float* Wvo  = (const float*)d_in[11];
  const float* bvo  = (const float*)d_in[12];
  const float* Wlo  = (const float*)d_in[13];
  const float* blo  = (const float*)d_in[14];

  float* out_xv = (float*)d_out;                       // 18432 x 1024
  float* out_xl = out_xv + (size_t)18432 * 1024;       // 4096 x 768

  bfu* ws   = (bfu*)d_ws;
  bfu* vb   = ws;                      // 18874368 (later aliased as xv bf16)
  bfu* lb   = vb   + 18874368;         // 3145728  (later aliased by colpart)
  bfu* wqv  = lb   + 3145728;          // 2097152  [Wvq ; Wvv] (2048x1024); tail aliased by colpart
  bfu* wklv = wqv  + 2097152;          // 1572864  [Wlk ; Wlv] (2048x768)
  bfu* wvo  = wklv + 1572864;          // 1048576
  bfu* wlo  = wvo  + 1048576;          // 786432
  bfu* Qb   = wlo  + 786432;           // 18874368  [18432][1024] bf16
  bfu* VVt  = Qb   + 18874368;         // 18874368  [bh][64][576]
  bfu* Kb   = VVt  + 18874368;         // 4194304   [4096][1024] (later aliased as xl bf16)
  bfu* LVt  = Kb   + 4194304;          // 4194304   [bh][64][128]
  bfu* PT   = LVt  + 4194304;          // 37748736  [bh][128][576]
  float* biasqv = (float*)(PT + 37748736);   // 2048 f32  [bvq ; bvv]
  float* biaskl = biasqv + 2048;             // 2048 f32  [blk ; blv]
  // colpart: 512*36*128 f32 = 9.44 MB, aliases lb+wqv (both dead by attention time)
  float* colpart = (float*)lb;

  // 1) converts + bias concat (d2d async copies are graph-capture safe)
  cvt_f32_bf16<<<cvt_grid(18874368 / 4), 256, 0, stream>>>(v, vb, 18874368 / 4);
  CvtArgs ca;
  ca.src[0] = lx;  ca.dst[0] = lb;             ca.n4[0] = 3145728 / 4;
  ca.src[1] = Wvq; ca.dst[1] = wqv;            ca.n4[1] = 1048576 / 4;
  ca.src[2] = Wvv; ca.dst[2] = wqv + 1048576;  ca.n4[2] = 1048576 / 4;
  ca.src[3] = Wlk; ca.dst[3] = wklv;           ca.n4[3] = 786432 / 4;
  ca.src[4] = Wlv; ca.dst[4] = wklv + 786432;  ca.n4[4] = 786432 / 4;
  ca.src[5] = Wvo; ca.dst[5] = wvo;            ca.n4[5] = 1048576 / 4;
  ca.src[6] = Wlo; ca.dst[6] = wlo;            ca.n4[6] = 786432 / 4;
  cvt_multi<<<dim3(1024, 7), 256, 0, stream>>>(ca);
  hipMemcpyAsync(biasqv,        bvq, 1024 * sizeof(float), hipMemcpyDeviceToDevice, stream);
  hipMemcpyAsync(biasqv + 1024, bvv, 1024 * sizeof(float), hipMemcpyDeviceToDevice, stream);
  hipMemcpyAsync(biaskl,        blk, 1024 * sizeof(float), hipMemcpyDeviceToDevice, stream);
  hipMemcpyAsync(biaskl + 1024, blv, 1024 * sizeof(float), hipMemcpyDeviceToDevice, stream);

  // 2) fused projection GEMMs: [Q | VVt] and [K | LVt]; row-major halves have ldc=1024
  gemm_bt<<<144 * 16, 256, 0, stream>>>(vb, wqv,  biasqv, Qb, nullptr, VVt, 576, 1024, 1024,
                                        18432, 2048, 1024, 16);
  gemm_bt<<<32 * 16,  256, 0, stream>>>(lb, wklv, biaskl, Kb, nullptr, LVt, 128, 1024, 1024,
                                        4096, 2048, 768, 16);

  // 3) attention: 1-wave blocks (xv -> vb alias, xl -> Kb alias)
  attn_xv<<<512 * 36, 64, 0, stream>>>(Qb, Kb, LVt, mask, vb, PT, colpart);
  attn_xl<<<512 * 8,  64, 0, stream>>>(PT, VVt, colpart, Kb);

  // 4) output GEMMs (f32 out)
  gemm_bt<<<144 * 8, 256, 0, stream>>>(vb, wvo, bvo, nullptr, out_xv, nullptr, 0, 1024, 1024,
                                       18432, 1024, 1024, 8);
  gemm_bt<<<32 * 6,  256, 0, stream>>>(Kb, wlo, blo, nullptr, out_xl, nullptr, 0, 768, 768,
                                       4096, 768, 1024, 6);
}